// Round 1
// baseline (1062.943 us; speedup 1.0000x reference)
//
#include <hip/hip_runtime.h>
#include <hip/hip_bf16.h>

typedef float f32x4 __attribute__((ext_vector_type(4)));
typedef __bf16 bf16x8 __attribute__((ext_vector_type(8)));

#define VSZ 32000
#define ESZ 256
#define NT 32
#define BB 64
#define TT 2048

// ---------------- weight prep: G[k2][n][cp] = sum_c fc_w[n,c] * w2[c,cp,k2] ----
__global__ __launch_bounds__(256) void prep_g(const float* __restrict__ fcw,
                                              const float* __restrict__ w2,
                                              float* __restrict__ G) {
  int tid = blockIdx.x * 256 + threadIdx.x;   // 24576 threads
  int cp = tid & 255;
  int rest = tid >> 8;       // 0..95
  int n = rest & 31;
  int k2 = rest >> 5;        // 0..2
  float acc = 0.f;
  for (int c = 0; c < 256; ++c)
    acc = fmaf(fcw[n * 256 + c], w2[(c * 256 + cp) * 3 + k2], acc);
  G[(k2 * 32 + n) * 256 + cp] = acc;
}

// ---------------- Wf[n][e][kk] (packed bf16 in MFMA B-frag layout), C0, CT, biases
__global__ __launch_bounds__(256) void prep_wf(const float* __restrict__ G,
                                               const float* __restrict__ w1,
                                               const float* __restrict__ b1,
                                               const float* __restrict__ b2,
                                               const float* __restrict__ fcw,
                                               const float* __restrict__ fcb,
                                               __bf16* __restrict__ wfb,
                                               float* __restrict__ C0,
                                               float* __restrict__ CT,
                                               float* __restrict__ bias_tot,
                                               float* __restrict__ c0v,
                                               float* __restrict__ cTv) {
  int tid = blockIdx.x * 256 + threadIdx.x;
  if (tid < 40960) {                 // Wf part: tid = (e*5 + kk)*32 + n
    int n = tid & 31;
    int r = tid >> 5;                // 0..1279
    int kk = r % 5;
    int e = r / 5;
    float acc = 0.f;
    #pragma unroll
    for (int k2 = 0; k2 < 3; ++k2) {
      int k1 = kk - k2;
      if (k1 < 0 || k1 > 2) continue;
      const float* g = G + (k2 * 32 + n) * 256;
      for (int cp = 0; cp < 256; ++cp)
        acc = fmaf(g[cp], w1[cp * 768 + e * 3 + k1], acc);
    }
    // pack into B-frag layout for mfma_f32_16x16x32_bf16:
    // B[k=e][j=kk*32+n], frag: lane = (j&15) | (((e>>3)&3)<<4), elem r = e&7
    int j = kk * 32 + n;
    int jt = j >> 4, jl = j & 15;
    int et = e >> 5, el = e & 31;
    int lane = jl | ((el >> 3) << 4);
    int rr = el & 7;
    wfb[((jt * 8 + et) * 64 + lane) * 8 + rr] = (__bf16)acc;
  } else if (tid < 57344) {          // C0 / CT
    int t2 = tid - 40960;
    int which = (t2 >= 8192);
    if (which) t2 -= 8192;
    int n = t2 & 31;
    int e = t2 >> 5;
    const float* g = G + ((which ? 2 : 0) * 32 + n) * 256;
    int k1 = which ? 0 : 2;
    float acc = 0.f;
    for (int cp = 0; cp < 256; ++cp)
      acc = fmaf(g[cp], w1[cp * 768 + e * 3 + k1], acc);
    (which ? CT : C0)[n * 256 + e] = acc;
  } else if (tid < 57376) {          // biases
    int n = tid - 57344;
    float bt = fcb[n];
    for (int c = 0; c < 256; ++c) bt = fmaf(fcw[n * 256 + c], b2[c], bt);
    float s0 = 0.f, s1 = 0.f, s2 = 0.f;
    const float* g0 = G + (0 * 32 + n) * 256;
    const float* g1 = G + (1 * 32 + n) * 256;
    const float* g2 = G + (2 * 32 + n) * 256;
    for (int cp = 0; cp < 256; ++cp) {
      s0 = fmaf(g0[cp], b1[cp], s0);
      s1 = fmaf(g1[cp], b1[cp], s1);
      s2 = fmaf(g2[cp], b1[cp], s2);
    }
    bias_tot[n] = bt + s0 + s1 + s2;
    c0v[n] = s0;
    cTv[n] = s2;
  }
}

// ---------------- P[v][kk][n] = sum_e emb[v,e] * Wf[n,e,kk]  (bf16 MFMA GEMM)
__global__ __launch_bounds__(256) void p_table(const float* __restrict__ emb,
                                               const __bf16* __restrict__ wfb,
                                               float* __restrict__ P) {
  int lane = threadIdx.x & 63;
  int gw = blockIdx.x * 4 + (threadIdx.x >> 6);  // 0..19999
  int mt = gw / 10, jt = gw % 10;
  int m = mt * 16 + (lane & 15);
  int q = lane >> 4;
  f32x4 acc = {0.f, 0.f, 0.f, 0.f};
  const float* arow = emb + m * 256 + q * 8;
  #pragma unroll
  for (int et = 0; et < 8; ++et) {
    f32x4 a0 = *(const f32x4*)(arow + et * 32);
    f32x4 a1 = *(const f32x4*)(arow + et * 32 + 4);
    bf16x8 af;
    af[0] = (__bf16)a0[0]; af[1] = (__bf16)a0[1];
    af[2] = (__bf16)a0[2]; af[3] = (__bf16)a0[3];
    af[4] = (__bf16)a1[0]; af[5] = (__bf16)a1[1];
    af[6] = (__bf16)a1[2]; af[7] = (__bf16)a1[3];
    bf16x8 bfr = *(const bf16x8*)(wfb + ((jt * 8 + et) * 64 + lane) * 8);
    acc = __builtin_amdgcn_mfma_f32_16x16x32_bf16(af, bfr, acc, 0, 0, 0);
  }
  // C layout: col = lane&15, row = (lane>>4)*4 + reg
  float* pp = P + (mt * 16 + q * 4) * 160 + jt * 16 + (lane & 15);
  pp[0] = acc[0]; pp[160] = acc[1]; pp[320] = acc[2]; pp[480] = acc[3];
}

// ---------------- logits L[b][t][n] = bias + sum_k P[idx[b,t+k-2]][k][:] - boundary fix
__global__ __launch_bounds__(256) void logits_k(const int* __restrict__ idx,
                                                const float* __restrict__ P,
                                                const float* __restrict__ bias_tot,
                                                const float* __restrict__ C0,
                                                const float* __restrict__ CT,
                                                const float* __restrict__ c0v,
                                                const float* __restrict__ cTv,
                                                const float* __restrict__ emb,
                                                float* __restrict__ L) {
  int tid = blockIdx.x * 256 + threadIdx.x;    // 2^20 threads
  int q = tid & 7;
  int t = (tid >> 3) & 2047;
  int b = tid >> 14;
  const int* ib = idx + b * 2048;
  f32x4 acc = *(const f32x4*)(bias_tot + q * 4);
  #pragma unroll
  for (int k = 0; k < 5; ++k) {
    int tt = t + k - 2;
    if (tt >= 0 && tt < 2048) {
      int v = ib[tt];
      acc += *(const f32x4*)(P + v * 160 + k * 32 + q * 4);
    }
  }
  if (t == 0) {
    int v0 = ib[0];
    const float* er = emb + v0 * 256;
    f32x4 d = *(const f32x4*)(c0v + q * 4);
    for (int e = 0; e < 256; ++e) {
      float x = er[e];
      d[0] = fmaf(C0[(q * 4 + 0) * 256 + e], x, d[0]);
      d[1] = fmaf(C0[(q * 4 + 1) * 256 + e], x, d[1]);
      d[2] = fmaf(C0[(q * 4 + 2) * 256 + e], x, d[2]);
      d[3] = fmaf(C0[(q * 4 + 3) * 256 + e], x, d[3]);
    }
    acc -= d;
  }
  if (t == 2047) {
    int vT = ib[2047];
    const float* er = emb + vT * 256;
    f32x4 d = *(const f32x4*)(cTv + q * 4);
    for (int e = 0; e < 256; ++e) {
      float x = er[e];
      d[0] = fmaf(CT[(q * 4 + 0) * 256 + e], x, d[0]);
      d[1] = fmaf(CT[(q * 4 + 1) * 256 + e], x, d[1]);
      d[2] = fmaf(CT[(q * 4 + 2) * 256 + e], x, d[2]);
      d[3] = fmaf(CT[(q * 4 + 3) * 256 + e], x, d[3]);
    }
    acc -= d;
  }
  *(f32x4*)(L + (b * 2048 + t) * 32 + q * 4) = acc;
}

// ---------------- TexpT[j][k] = exp(trans[k][j])
__global__ void texp_k(const float* __restrict__ trans, float* __restrict__ texpT) {
  int tid = threadIdx.x;          // 1024
  int j = tid >> 5, k = tid & 31;
  texpT[j * 32 + k] = __expf(trans[k * 32 + j]) * 1.0f;
}

// ---------------- CRF stage 1: per (b, chunk, row i) 64-step vec x mat chain
// v <- v * Texp * diag(exp(em_t) * 2^-5)
__global__ __launch_bounds__(256) void crf_stage1(const float* __restrict__ L,
                                                  const float* __restrict__ texpT,
                                                  float* __restrict__ Pc) {
  int lane = threadIdx.x & 63;
  int waveId = blockIdx.x * 4 + (threadIdx.x >> 6);   // 0..1023
  int p = waveId * 2 + (lane >> 5);                   // 0..2047, p = c*64 + b
  int c = p >> 6;
  int b = p & 63;
  int i = lane & 31;
  float v[32];
  #pragma unroll
  for (int j = 0; j < 32; ++j) v[j] = (j == i) ? 1.0f : 0.0f;
  int tstart = c * 64 + 1;
  int nsteps = (c == 31) ? 63 : 64;     // wave-uniform (both halves share c)
  const float* Lb = L + (b * 2048) * 32;
  for (int s = 0; s < nsteps; ++s) {
    const float* tp = texpT;
    asm volatile("" : "+v"(tp));        // defeat LICM hoisting of 1024 Texp loads
    const float* em = Lb + (tstart + s) * 32;
    f32x4 e4[8];
    #pragma unroll
    for (int jq = 0; jq < 8; ++jq) e4[jq] = *(const f32x4*)(em + jq * 4);
    float out[32];
    #pragma unroll
    for (int j = 0; j < 32; ++j) {
      const float* tc = tp + j * 32;
      float acc = 0.f;
      #pragma unroll
      for (int k = 0; k < 32; ++k) acc = fmaf(v[k], tc[k], acc);
      out[j] = acc;
    }
    #pragma unroll
    for (int j = 0; j < 32; ++j) {
      float sc = exp2f(fmaf(e4[j >> 2][j & 3], 1.44269504f, -5.0f));
      v[j] = out[j] * sc;
    }
  }
  float* dst = Pc + (((b * 32 + c) * 32) + i) * 32;
  #pragma unroll
  for (int jq = 0; jq < 8; ++jq) {
    f32x4 w = {v[jq * 4], v[jq * 4 + 1], v[jq * 4 + 2], v[jq * 4 + 3]};
    *(f32x4*)(dst + jq * 4) = w;
  }
}

// ---------------- CRF stage 2: per-batch sequential combine of 32 chunk matrices
__global__ __launch_bounds__(64) void crf_stage2(const float* __restrict__ L,
                                                 const float* __restrict__ Pc,
                                                 const float* __restrict__ start_t,
                                                 const float* __restrict__ end_t,
                                                 float* __restrict__ out) {
  int b = blockIdx.x;
  int j = threadIdx.x & 31;
  float u = __expf(start_t[j] + L[b * 2048 * 32 + j]);
  float logacc = 0.f;
  for (int c = 0; c < 32; ++c) {
    const float* M = Pc + ((b * 32 + c) * 32) * 32;
    float nu = 0.f;
    #pragma unroll
    for (int k = 0; k < 32; ++k) {
      float uk = __shfl(u, k, 32);
      nu = fmaf(uk, M[k * 32 + j], nu);
    }
    float ssum = nu;
    #pragma unroll
    for (int o = 1; o < 32; o <<= 1) ssum += __shfl_xor(ssum, o, 32);
    u = nu / ssum;
    logacc += logf(ssum);
  }
  float term = u * __expf(end_t[j]);
  #pragma unroll
  for (int o = 1; o < 32; o <<= 1) term += __shfl_xor(term, o, 32);
  if (threadIdx.x == 0)
    out[b] = logacc + logf(term) + (float)(2047.0 * 5.0 * 0.69314718055994530942);
}

extern "C" void kernel_launch(void* const* d_in, const int* in_sizes, int n_in,
                              void* d_out, int out_size, void* d_ws, size_t ws_size,
                              hipStream_t stream) {
  const int*   idx  = (const int*)d_in[0];
  const float* emb  = (const float*)d_in[1];
  const float* w1   = (const float*)d_in[2];
  const float* b1   = (const float*)d_in[3];
  const float* w2   = (const float*)d_in[4];
  const float* b2   = (const float*)d_in[5];
  const float* fcw  = (const float*)d_in[6];
  const float* fcb  = (const float*)d_in[7];
  const float* trn  = (const float*)d_in[8];
  const float* st   = (const float*)d_in[9];
  const float* en   = (const float*)d_in[10];

  char* ws = (char*)d_ws;
  float*  P     = (float*)(ws + 0);            // 20,480,000 B
  float*  L     = (float*)(ws + 20480000);     // 16,777,216 B
  float*  Pc    = (float*)(ws + 37257216);     //  8,388,608 B
  __bf16* WfB   = (__bf16*)(ws + 45645824);    //     81,920 B
  float*  G     = (float*)(ws + 45727744);     //     98,304 B
  float*  C0    = (float*)(ws + 45826048);     //     32,768 B
  float*  CT    = (float*)(ws + 45858816);     //     32,768 B
  float*  bias  = (float*)(ws + 45891584);     //        128 B
  float*  c0v   = (float*)(ws + 45891712);     //        128 B
  float*  cTv   = (float*)(ws + 45891840);     //        128 B
  float*  TexpT = (float*)(ws + 45891968);     //      4,096 B
  // total ws need ~45.9 MB

  prep_g   <<<96,   256, 0, stream>>>(fcw, w2, G);
  prep_wf  <<<225,  256, 0, stream>>>(G, w1, b1, b2, fcw, fcb, WfB, C0, CT, bias, c0v, cTv);
  texp_k   <<<1,   1024, 0, stream>>>(trn, TexpT);
  p_table  <<<5000, 256, 0, stream>>>(emb, WfB, P);
  logits_k <<<4096, 256, 0, stream>>>(idx, P, bias, C0, CT, c0v, cTv, emb, L);
  crf_stage1<<<256, 256, 0, stream>>>(L, TexpT, Pc);
  crf_stage2<<<64,   64, 0, stream>>>(L, Pc, st, en, (float*)d_out);
}

// Round 2
// 268.592 us; speedup vs baseline: 3.9575x; 3.9575x over previous
//
#include <hip/hip_runtime.h>
#include <hip/hip_bf16.h>

typedef float f32x4 __attribute__((ext_vector_type(4)));
typedef __bf16 bf16x8 __attribute__((ext_vector_type(8)));
typedef __bf16 bf16x4 __attribute__((ext_vector_type(4)));

// ---------------- weight prep: G[k2][n][cp] = sum_c fc_w[n,c] * w2[c,cp,k2] ----
__global__ __launch_bounds__(256) void prep_g(const float* __restrict__ fcw,
                                              const float* __restrict__ w2,
                                              float* __restrict__ G) {
  int tid = blockIdx.x * 256 + threadIdx.x;   // 24576 threads
  int cp = tid & 255;
  int rest = tid >> 8;       // 0..95
  int n = rest & 31;
  int k2 = rest >> 5;        // 0..2
  float acc = 0.f;
  for (int c = 0; c < 256; ++c)
    acc = fmaf(fcw[n * 256 + c], w2[(c * 256 + cp) * 3 + k2], acc);
  G[(k2 * 32 + n) * 256 + cp] = acc;
}

// ---------------- Wf[n][e][kk] (packed bf16 in MFMA B-frag layout), C0, CT, biases
__global__ __launch_bounds__(256) void prep_wf(const float* __restrict__ G,
                                               const float* __restrict__ w1,
                                               const float* __restrict__ b1,
                                               const float* __restrict__ b2,
                                               const float* __restrict__ fcw,
                                               const float* __restrict__ fcb,
                                               __bf16* __restrict__ wfb,
                                               float* __restrict__ C0,
                                               float* __restrict__ CT,
                                               float* __restrict__ bias_tot,
                                               float* __restrict__ c0v,
                                               float* __restrict__ cTv) {
  int tid = blockIdx.x * 256 + threadIdx.x;
  if (tid < 40960) {                 // Wf part: tid = (e*5 + kk)*32 + n
    int n = tid & 31;
    int r = tid >> 5;                // 0..1279
    int kk = r % 5;
    int e = r / 5;
    float acc = 0.f;
    #pragma unroll
    for (int k2 = 0; k2 < 3; ++k2) {
      int k1 = kk - k2;
      if (k1 < 0 || k1 > 2) continue;
      const float* g = G + (k2 * 32 + n) * 256;
      for (int cp = 0; cp < 256; ++cp)
        acc = fmaf(g[cp], w1[cp * 768 + e * 3 + k1], acc);
    }
    // pack into B-frag layout for mfma_f32_16x16x32_bf16:
    // B[k=e][j=kk*32+n], frag: lane = (j&15) | (((e>>3)&3)<<4), elem r = e&7
    int j = kk * 32 + n;
    int jt = j >> 4, jl = j & 15;
    int et = e >> 5, el = e & 31;
    int lane = jl | ((el >> 3) << 4);
    int rr = el & 7;
    wfb[((jt * 8 + et) * 64 + lane) * 8 + rr] = (__bf16)acc;
  } else if (tid < 57344) {          // C0 / CT
    int t2 = tid - 40960;
    int which = (t2 >= 8192);
    if (which) t2 -= 8192;
    int n = t2 & 31;
    int e = t2 >> 5;
    const float* g = G + ((which ? 2 : 0) * 32 + n) * 256;
    int k1 = which ? 0 : 2;
    float acc = 0.f;
    for (int cp = 0; cp < 256; ++cp)
      acc = fmaf(g[cp], w1[cp * 768 + e * 3 + k1], acc);
    (which ? CT : C0)[n * 256 + e] = acc;
  } else if (tid < 57376) {          // biases
    int n = tid - 57344;
    float bt = fcb[n];
    for (int c = 0; c < 256; ++c) bt = fmaf(fcw[n * 256 + c], b2[c], bt);
    float s0 = 0.f, s1 = 0.f, s2 = 0.f;
    const float* g0 = G + (0 * 32 + n) * 256;
    const float* g1 = G + (1 * 32 + n) * 256;
    const float* g2 = G + (2 * 32 + n) * 256;
    for (int cp = 0; cp < 256; ++cp) {
      s0 = fmaf(g0[cp], b1[cp], s0);
      s1 = fmaf(g1[cp], b1[cp], s1);
      s2 = fmaf(g2[cp], b1[cp], s2);
    }
    bias_tot[n] = bt + s0 + s1 + s2;
    c0v[n] = s0;
    cTv[n] = s2;
  }
}

// ---------------- P[v][kk][n] = sum_e emb[v,e] * Wf[n,e,kk]  (bf16 MFMA GEMM)
// One wave handles one mt (16 vocab rows) for ALL 10 jt tiles: emb read once.
__global__ __launch_bounds__(256) void p_table(const float* __restrict__ emb,
                                               const __bf16* __restrict__ wfb,
                                               float* __restrict__ P) {
  int lane = threadIdx.x & 63;
  int mt = blockIdx.x * 4 + (threadIdx.x >> 6);  // 0..1999
  int ln = lane & 15;
  int q = lane >> 4;
  int m = mt * 16 + ln;
  f32x4 acc[10];
  #pragma unroll
  for (int jt = 0; jt < 10; ++jt) acc[jt] = (f32x4){0.f, 0.f, 0.f, 0.f};
  const float* arow = emb + m * 256 + q * 8;
  #pragma unroll
  for (int et = 0; et < 8; ++et) {
    f32x4 a0 = *(const f32x4*)(arow + et * 32);
    f32x4 a1 = *(const f32x4*)(arow + et * 32 + 4);
    bf16x8 af;
    af[0] = (__bf16)a0[0]; af[1] = (__bf16)a0[1];
    af[2] = (__bf16)a0[2]; af[3] = (__bf16)a0[3];
    af[4] = (__bf16)a1[0]; af[5] = (__bf16)a1[1];
    af[6] = (__bf16)a1[2]; af[7] = (__bf16)a1[3];
    #pragma unroll
    for (int jt = 0; jt < 10; ++jt) {
      bf16x8 bfr = *(const bf16x8*)(wfb + ((jt * 8 + et) * 64 + lane) * 8);
      acc[jt] = __builtin_amdgcn_mfma_f32_16x16x32_bf16(af, bfr, acc[jt], 0, 0, 0);
    }
  }
  // C layout: col = lane&15, row = (lane>>4)*4 + reg
  #pragma unroll
  for (int jt = 0; jt < 10; ++jt) {
    float* pp = P + (mt * 16 + q * 4) * 160 + jt * 16 + ln;
    pp[0] = acc[jt][0]; pp[160] = acc[jt][1]; pp[320] = acc[jt][2]; pp[480] = acc[jt][3];
  }
}

// ---------------- logits -> Lexp[b][t][n] = exp(logit) * 2^-5
__global__ __launch_bounds__(256) void logits_k(const int* __restrict__ idx,
                                                const float* __restrict__ P,
                                                const float* __restrict__ bias_tot,
                                                const float* __restrict__ C0,
                                                const float* __restrict__ CT,
                                                const float* __restrict__ c0v,
                                                const float* __restrict__ cTv,
                                                const float* __restrict__ emb,
                                                float* __restrict__ L) {
  int tid = blockIdx.x * 256 + threadIdx.x;    // 2^20 threads
  int q = tid & 7;
  int t = (tid >> 3) & 2047;
  int b = tid >> 14;
  const int* ib = idx + b * 2048;
  f32x4 acc = *(const f32x4*)(bias_tot + q * 4);
  #pragma unroll
  for (int k = 0; k < 5; ++k) {
    int tt = t + k - 2;
    if (tt >= 0 && tt < 2048) {
      int v = ib[tt];
      acc += *(const f32x4*)(P + v * 160 + k * 32 + q * 4);
    }
  }
  if (t == 0) {
    int v0 = ib[0];
    const float* er = emb + v0 * 256;
    f32x4 d = *(const f32x4*)(c0v + q * 4);
    for (int e = 0; e < 256; ++e) {
      float x = er[e];
      d[0] = fmaf(C0[(q * 4 + 0) * 256 + e], x, d[0]);
      d[1] = fmaf(C0[(q * 4 + 1) * 256 + e], x, d[1]);
      d[2] = fmaf(C0[(q * 4 + 2) * 256 + e], x, d[2]);
      d[3] = fmaf(C0[(q * 4 + 3) * 256 + e], x, d[3]);
    }
    acc -= d;
  }
  if (t == 2047) {
    int vT = ib[2047];
    const float* er = emb + vT * 256;
    f32x4 d = *(const f32x4*)(cTv + q * 4);
    for (int e = 0; e < 256; ++e) {
      float x = er[e];
      d[0] = fmaf(CT[(q * 4 + 0) * 256 + e], x, d[0]);
      d[1] = fmaf(CT[(q * 4 + 1) * 256 + e], x, d[1]);
      d[2] = fmaf(CT[(q * 4 + 2) * 256 + e], x, d[2]);
      d[3] = fmaf(CT[(q * 4 + 3) * 256 + e], x, d[3]);
    }
    acc -= d;
  }
  f32x4 r;
  r[0] = __expf(acc[0]) * 0.03125f;
  r[1] = __expf(acc[1]) * 0.03125f;
  r[2] = __expf(acc[2]) * 0.03125f;
  r[3] = __expf(acc[3]) * 0.03125f;
  *(f32x4*)(L + (b * 2048 + t) * 32 + q * 4) = r;
}

// ---------------- TexpT[j][k] = exp(trans[k][j])
__global__ void texp_k(const float* __restrict__ trans, float* __restrict__ texpT) {
  int tid = threadIdx.x;          // 1024
  int j = tid >> 5, k = tid & 31;
  texpT[j * 32 + k] = __expf(trans[k * 32 + j]);
}

// ---------------- CRF stage 1: one wave per (b, chunk): 64-step 32x32 MFMA chain
// Transposed form: S <- (D_t * Texp^T) * S, S0 = I; final M_c = S^T.
// A frag (16x16x32): A[m=lane&15][k=(lane>>4)*8+e]; B: B[k=(lane>>4)*8+e][n=lane&15]
// C: col=lane&15, row=(lane>>4)*4+reg.
__global__ __launch_bounds__(256) void crf_stage1(const float* __restrict__ Lexp,
                                                  const float* __restrict__ texpT,
                                                  float* __restrict__ Pc) {
  __shared__ __bf16 sl[4][32 * 40];   // wave-private S scratch, padded stride 40
  int lane = threadIdx.x & 63;
  int w = threadIdx.x >> 6;
  int chain = blockIdx.x * 4 + w;     // 0..2047
  int c = chain >> 6;                 // chunk 0..31
  int b = chain & 63;
  int ln = lane & 15;
  int q = lane >> 4;
  // Texp^T rows for A: tA[it][e] = Texp^T[it*16+ln][q*8+e]
  float tA0[8], tA1[8];
  #pragma unroll
  for (int e = 0; e < 8; ++e) {
    tA0[e] = texpT[(ln) * 32 + q * 8 + e];
    tA1[e] = texpT[(16 + ln) * 32 + q * 8 + e];
  }
  // init B frags: S = I
  bf16x8 bf0, bf1;
  #pragma unroll
  for (int e = 0; e < 8; ++e) {
    int k = q * 8 + e;
    bf0[e] = (k == ln) ? (__bf16)1.0f : (__bf16)0.0f;
    bf1[e] = (k == 16 + ln) ? (__bf16)1.0f : (__bf16)0.0f;
  }
  int tstart = c * 64 + 1;
  int nsteps = (c == 31) ? 63 : 64;
  const float* Le = Lexp + (b * 2048 + tstart) * 32;
  __bf16* myS = &sl[w][0];
  f32x4 c00, c01, c10, c11;
  for (int s = 0; s < nsteps; ++s) {
    float sc0 = Le[s * 32 + ln];
    float sc1 = Le[s * 32 + ln + 16];
    bf16x8 a0, a1;
    #pragma unroll
    for (int e = 0; e < 8; ++e) {
      a0[e] = (__bf16)(sc0 * tA0[e]);
      a1[e] = (__bf16)(sc1 * tA1[e]);
    }
    f32x4 z = {0.f, 0.f, 0.f, 0.f};
    c00 = __builtin_amdgcn_mfma_f32_16x16x32_bf16(a0, bf0, z, 0, 0, 0);
    c01 = __builtin_amdgcn_mfma_f32_16x16x32_bf16(a0, bf1, z, 0, 0, 0);
    c10 = __builtin_amdgcn_mfma_f32_16x16x32_bf16(a1, bf0, z, 0, 0, 0);
    c11 = __builtin_amdgcn_mfma_f32_16x16x32_bf16(a1, bf1, z, 0, 0, 0);
    if (s + 1 < nsteps) {
      // S'[row][col]: tile(it,nt): row=it*16+q*4+reg, col=nt*16+ln
      // store transposed into LDS: myS[col*40 + row] so B-read is contiguous in k
      bf16x4 w00, w01, w10, w11;
      #pragma unroll
      for (int r = 0; r < 4; ++r) {
        w00[r] = (__bf16)c00[r]; w01[r] = (__bf16)c01[r];
        w10[r] = (__bf16)c10[r]; w11[r] = (__bf16)c11[r];
      }
      *(bf16x4*)(myS + (ln) * 40      + q * 4)      = w00;  // it0 nt0
      *(bf16x4*)(myS + (16 + ln) * 40 + q * 4)      = w01;  // it0 nt1
      *(bf16x4*)(myS + (ln) * 40      + 16 + q * 4) = w10;  // it1 nt0
      *(bf16x4*)(myS + (16 + ln) * 40 + 16 + q * 4) = w11;  // it1 nt1
      // next B frags: B[k=q*8+e][n=nt*16+ln] = myS[n*40 + k]
      bf0 = *(const bf16x8*)(myS + (ln) * 40 + q * 8);
      bf1 = *(const bf16x8*)(myS + (16 + ln) * 40 + q * 8);
    }
  }
  // Pc[b][c][i][j] = M[i][j] = S[j][i]; tile(it,nt): i=nt*16+ln, j=it*16+q*4+reg
  float* dst = Pc + ((b * 32 + c) * 32) * 32;
  *(f32x4*)(dst + (ln) * 32      + q * 4)      = c00;
  *(f32x4*)(dst + (16 + ln) * 32 + q * 4)      = c01;
  *(f32x4*)(dst + (ln) * 32      + 16 + q * 4) = c10;
  *(f32x4*)(dst + (16 + ln) * 32 + 16 + q * 4) = c11;
}

// ---------------- CRF stage 2: per-batch sequential combine of 32 chunk matrices
__global__ __launch_bounds__(64) void crf_stage2(const float* __restrict__ Lexp,
                                                 const float* __restrict__ Pc,
                                                 const float* __restrict__ start_t,
                                                 const float* __restrict__ end_t,
                                                 float* __restrict__ out) {
  int b = blockIdx.x;
  int j = threadIdx.x & 31;
  // alpha0: exp(start + em0) = exp(start) * Lexp[b][0][j] * 32
  float u = __expf(start_t[j]) * Lexp[b * 2048 * 32 + j] * 32.f;
  float logacc = 0.f;
  for (int c = 0; c < 32; ++c) {
    const float* M = Pc + ((b * 32 + c) * 32) * 32;
    float nu = 0.f;
    #pragma unroll
    for (int k = 0; k < 32; ++k) {
      float uk = __shfl(u, k, 32);
      nu = fmaf(uk, M[k * 32 + j], nu);
    }
    float ssum = nu;
    #pragma unroll
    for (int o = 1; o < 32; o <<= 1) ssum += __shfl_xor(ssum, o, 32);
    u = nu / ssum;
    logacc += logf(ssum);
  }
  float term = u * __expf(end_t[j]);
  #pragma unroll
  for (int o = 1; o < 32; o <<= 1) term += __shfl_xor(term, o, 32);
  if (threadIdx.x == 0)
    out[b] = logacc + logf(term) + (float)(2047.0 * 5.0 * 0.69314718055994530942);
}

extern "C" void kernel_launch(void* const* d_in, const int* in_sizes, int n_in,
                              void* d_out, int out_size, void* d_ws, size_t ws_size,
                              hipStream_t stream) {
  const int*   idx  = (const int*)d_in[0];
  const float* emb  = (const float*)d_in[1];
  const float* w1   = (const float*)d_in[2];
  const float* b1   = (const float*)d_in[3];
  const float* w2   = (const float*)d_in[4];
  const float* b2   = (const float*)d_in[5];
  const float* fcw  = (const float*)d_in[6];
  const float* fcb  = (const float*)d_in[7];
  const float* trn  = (const float*)d_in[8];
  const float* st   = (const float*)d_in[9];
  const float* en   = (const float*)d_in[10];

  char* ws = (char*)d_ws;
  float*  P     = (float*)(ws + 0);            // 20,480,000 B
  float*  L     = (float*)(ws + 20480000);     // 16,777,216 B  (holds Lexp)
  float*  Pc    = (float*)(ws + 37257216);     //  8,388,608 B
  __bf16* WfB   = (__bf16*)(ws + 45645824);    //     81,920 B
  float*  G     = (float*)(ws + 45727744);     //     98,304 B
  float*  C0    = (float*)(ws + 45826048);     //     32,768 B
  float*  CT    = (float*)(ws + 45858816);     //     32,768 B
  float*  bias  = (float*)(ws + 45891584);     //        128 B
  float*  c0v   = (float*)(ws + 45891712);     //        128 B
  float*  cTv   = (float*)(ws + 45891840);     //        128 B
  float*  TexpT = (float*)(ws + 45891968);     //      4,096 B

  prep_g    <<<96,   256, 0, stream>>>(fcw, w2, G);
  prep_wf   <<<225,  256, 0, stream>>>(G, w1, b1, b2, fcw, fcb, WfB, C0, CT, bias, c0v, cTv);
  texp_k    <<<1,   1024, 0, stream>>>(trn, TexpT);
  p_table   <<<500,  256, 0, stream>>>(emb, WfB, P);
  logits_k  <<<4096, 256, 0, stream>>>(idx, P, bias, C0, CT, c0v, cTv, emb, L);
  crf_stage1<<<512,  256, 0, stream>>>(L, TexpT, Pc);
  crf_stage2<<<64,    64, 0, stream>>>(L, Pc, st, en, (float*)d_out);
}